// Round 6
// baseline (2758.075 us; speedup 1.0000x reference)
//
#include <hip/hip_runtime.h>
#include <math.h>

// Diffusion sampler: 49 sequential steps, rows independent.
// Round 6: fix the L2-BW bound. 256 blocks x 512 threads, 16 rows/block.
// Waves are COLUMN-tiled: wave w owns output cols [32w,32w+32); each lane
// computes 2 rows x 4 cols. Weights stream ONCE per CU per step (852KB)
// instead of once per WAVE (6.8MB) -> 8x less L2 traffic. 3 barriers/step.
// Per-output summation order identical to round 5 (bitwise-same results).
// All f32. PRNG: JAX threefry2x32, partitionable mode.

#define DXY 288
#define HID 256
#define NTHR 512
#define XYP 292                 // xy_s row stride (pad: 292 % 32 == 4)
#define HP  260                 // h_s row stride  (pad: 260 % 32 == 4)
#define OUT_Y_OFF 1048576
#define OUT_T_OFF 1179648
#define CT_FLOATS (50 * 512)
#define STEP_OFF  CT_FLOATS

typedef unsigned int u32;

__device__ __forceinline__ void tf2x32(u32 k0, u32 k1, u32 x0, u32 x1, u32& o0, u32& o1) {
  u32 ks2 = k0 ^ k1 ^ 0x1BD11BDAu;
#define TFR(r) { x0 += x1; x1 = (x1 << (r)) | (x1 >> (32 - (r))); x1 ^= x0; }
  x0 += k0; x1 += k1;
  TFR(13) TFR(15) TFR(26) TFR(6)
  x0 += k1;  x1 += ks2 + 1u;
  TFR(17) TFR(29) TFR(16) TFR(24)
  x0 += ks2; x1 += k0 + 2u;
  TFR(13) TFR(15) TFR(26) TFR(6)
  x0 += k0;  x1 += k1 + 3u;
  TFR(17) TFR(29) TFR(16) TFR(24)
  x0 += k1;  x1 += ks2 + 4u;
  TFR(13) TFR(15) TFR(26) TFR(6)
  x0 += ks2; x1 += k0 + 5u;
#undef TFR
  o0 = x0; o1 = x1;
}

__device__ __forceinline__ u32 pbits(u32 ka, u32 kb, u32 j) {
  u32 w0, w1;
  tf2x32(ka, kb, 0u, j, w0, w1);
  return w0 ^ w1;
}

__device__ __forceinline__ float u01f(u32 bits) {
  union { u32 i; float f; } v;
  v.i = (bits >> 9) | 0x3F800000u;
  return v.f - 1.0f;
}

// XLA f32 ErfInv (Giles polynomial)
__device__ __forceinline__ float erfinv32(float x) {
  float w = -log1pf(-x * x);
  float p;
  if (w < 5.0f) {
    w -= 2.5f;
    p = 2.81022636e-08f;
    p = fmaf(p, w, 3.43273939e-07f);
    p = fmaf(p, w, -3.5233877e-06f);
    p = fmaf(p, w, -4.39150654e-06f);
    p = fmaf(p, w, 0.00021858087f);
    p = fmaf(p, w, -0.00125372503f);
    p = fmaf(p, w, -0.00417768164f);
    p = fmaf(p, w, 0.246640727f);
    p = fmaf(p, w, 1.50140941f);
  } else {
    w = sqrtf(w) - 3.0f;
    p = -0.000200214257f;
    p = fmaf(p, w, 0.000100950558f);
    p = fmaf(p, w, 0.00134934322f);
    p = fmaf(p, w, -0.00367342844f);
    p = fmaf(p, w, 0.00573950773f);
    p = fmaf(p, w, -0.0076224613f);
    p = fmaf(p, w, 0.00943887047f);
    p = fmaf(p, w, 1.00167406f);
    p = fmaf(p, w, 2.83297682f);
  }
  return p * x;
}

__device__ __forceinline__ float nrmf(u32 bits) {
  float val = fmaf(u01f(bits), 2.0f, -0.99999994f);
  return 1.41421356f * erfinv32(val);
}
__device__ __forceinline__ float gumf(u32 bits) {
  float u = fmaxf(u01f(bits), 1.17549435e-38f);
  return -logf(-logf(u));
}
__device__ __forceinline__ float siluf(float x) {
  return x / (1.0f + expf(-x));
}
__device__ __forceinline__ void fma4(float a, const float4& b, float* acc) {
  acc[0] = fmaf(a, b.x, acc[0]);
  acc[1] = fmaf(a, b.y, acc[1]);
  acc[2] = fmaf(a, b.z, acc[2]);
  acc[3] = fmaf(a, b.w, acc[3]);
}

// ---- precompute: Ct[t][k][c] and step scalars into ws ----
__global__ void precompute_ct(
    const float* __restrict__ t_embed,
    const float* __restrict__ tm_w1, const float* __restrict__ tm_b1,
    const float* __restrict__ tm_w2, const float* __restrict__ tm_b2,
    const float* __restrict__ tr_w1, const float* __restrict__ tr_b1,
    float* __restrict__ ws)
{
  const int t = blockIdx.x + 1;       // 1..49
  const int c = threadIdx.x;          // 0..255
  __shared__ float tmpre[HID];
  __shared__ float tmv[HID];
  const float tau = (float)t / 50.0f;

  tmpre[c] = siluf(fmaf(tau, tm_w1[c], tm_b1[c]));
  __syncthreads();
  {
    float acc = tm_b2[c];
    for (int i = 0; i < HID; i++)
      acc = fmaf(tmpre[i], tm_w2[i * HID + c], acc);
    tmv[c] = acc;
  }
  __syncthreads();
  float D = 0.f;
  for (int i = 0; i < HID; i++)
    D = fmaf(tmv[i], tr_w1[(544 + i) * HID + c], D);
  float ce0 = tr_b1[c], ce1 = tr_b1[c];
  for (int i = 0; i < HID; i++) {
    ce0 = fmaf(t_embed[i], tr_w1[(288 + i) * HID + c], ce0);
    ce1 = fmaf(t_embed[HID + i], tr_w1[(288 + i) * HID + c], ce1);
  }
  ws[t * 512 + c] = ce0 + D;
  ws[t * 512 + 256 + c] = ce1 + D;

  if (c == 0) {
    const double lt = 6.214608098422191;  // ln 500
    float sig_t = (float)(0.002 * exp(((double)t / 50.0) * lt));
    float sig_p = (float)(0.002 * exp(((double)(t - 1) / 50.0) * lt));
    float stepf = sig_t * sig_t - sig_p * sig_p;
    ws[STEP_OFF + 2 * t] = stepf;
    ws[STEP_OFF + 2 * t + 1] = sqrtf(stepf);
  }
}

// ---- main sampler: column-tiled waves, weights stream once per CU ----
__global__ __launch_bounds__(NTHR, 2) void sampler_k(
    const float* __restrict__ xy0, const int* __restrict__ t0,
    const float* __restrict__ tr_w1,
    const float* __restrict__ tr_w2, const float* __restrict__ tr_b2,
    const float* __restrict__ sh_w, const float* __restrict__ sh_b,
    const float* __restrict__ ch_w, const float* __restrict__ ch_b,
    const float* __restrict__ ws,
    float* __restrict__ out)
{
  __shared__ float xy_s[16][XYP];   // 18.7 KB
  __shared__ float h1_s[16][HP];    // 16.6 KB
  __shared__ float h2_s[16][HP];    // 16.6 KB
  __shared__ float ct_s[2][HID];    // 2 KB (staged per step)
  __shared__ int tcur_s[16];

  const int tid = threadIdx.x;
  const int lane = tid & 63;
  const int w = tid >> 6;                    // wave id: col tile [32w, 32w+32)
  const int row0g = blockIdx.x * 16;

  const int r0 = lane >> 3;                  // rows r0, r0+8
  const int r1 = r0 + 8;
  const int cg = w * 32 + (lane & 7) * 4;    // 4 output cols (GEMM tiles)
  const int rE = lane >> 2;                  // G3 extra: 16 rows x 4 cols/wave
  const int cE = 256 + w * 4 + (lane & 3);

  // ---- prologue: load xy, t0, Ct(t=49) ----
  for (int idx = tid; idx < 16 * (DXY / 4); idx += NTHR) {
    int r = idx / (DXY / 4);
    int q = idx - r * (DXY / 4);
    *(float4*)&xy_s[r][q * 4] = *(const float4*)(xy0 + (row0g + r) * DXY + q * 4);
  }
  if (tid < 16) tcur_s[tid] = t0[row0g + tid];
  ((float*)ct_s)[tid] = ws[49 * 512 + tid];

  // ---- hoisted constants ----
  float chw0[4], chw1[4];                    // logits: cols lane*4..+3
  #pragma unroll
  for (int j = 0; j < 4; j++) {
    chw0[j] = ch_w[(lane * 4 + j) * 2 + 0];
    chw1[j] = ch_w[(lane * 4 + j) * 2 + 1];
  }
  const float4 b2r = *(const float4*)(tr_b2 + cg);
  const float cb0 = ch_b[0], cb1 = ch_b[1];
  const float4 sbm = *(const float4*)(sh_b + cg);
  const float sbE = sh_b[cE];
  __syncthreads();

  #pragma unroll 1
  for (int t_idx = 49; t_idx >= 1; --t_idx) {
    const float stepf = ws[STEP_OFF + 2 * t_idx];
    const float sstep = ws[STEP_OFF + 2 * t_idx + 1];

    u32 f0, f1, k1a, k1b, k2a, k2b;
    tf2x32(0u, 42u, 0u, (u32)t_idx, f0, f1);
    tf2x32(f0, f1, 0u, 0u, k1a, k1b);
    tf2x32(f0, f1, 0u, 1u, k2a, k2b);

    // ---- G1: h1 = silu(xy @ W1[0:288] + Ct[t]) ----
    {
      const int tc0 = tcur_s[r0], tc1 = tcur_s[r1];
      float aA[4] = {0.f, 0.f, 0.f, 0.f};
      float aB[4] = {0.f, 0.f, 0.f, 0.f};
      const float* wp = tr_w1 + cg;
      #pragma unroll 4
      for (int i = 0; i < DXY; i += 4) {
        float4 xA = *(const float4*)&xy_s[r0][i];
        float4 xB = *(const float4*)&xy_s[r1][i];
        float4 b0 = *(const float4*)(wp + (i + 0) * HID);
        float4 b1 = *(const float4*)(wp + (i + 1) * HID);
        float4 b2 = *(const float4*)(wp + (i + 2) * HID);
        float4 b3 = *(const float4*)(wp + (i + 3) * HID);
        fma4(xA.x, b0, aA); fma4(xA.y, b1, aA); fma4(xA.z, b2, aA); fma4(xA.w, b3, aA);
        fma4(xB.x, b0, aB); fma4(xB.y, b1, aB); fma4(xB.z, b2, aB); fma4(xB.w, b3, aB);
      }
      const float4 ctA = *(const float4*)&ct_s[tc0][cg];
      const float4 ctB = *(const float4*)&ct_s[tc1][cg];
      float4 oA, oB;
      oA.x = siluf(aA[0] + ctA.x); oA.y = siluf(aA[1] + ctA.y);
      oA.z = siluf(aA[2] + ctA.z); oA.w = siluf(aA[3] + ctA.w);
      oB.x = siluf(aB[0] + ctB.x); oB.y = siluf(aB[1] + ctB.y);
      oB.z = siluf(aB[2] + ctB.z); oB.w = siluf(aB[3] + ctB.w);
      *(float4*)&h1_s[r0][cg] = oA;
      *(float4*)&h1_s[r1][cg] = oB;
    }
    __syncthreads();   // h1 ready

    // ---- G2: h2 = silu(h1 @ W2 + b2) ----
    {
      float aA[4] = {0.f, 0.f, 0.f, 0.f};
      float aB[4] = {0.f, 0.f, 0.f, 0.f};
      const float* wp = tr_w2 + cg;
      #pragma unroll 4
      for (int i = 0; i < HID; i += 4) {
        float4 hA = *(const float4*)&h1_s[r0][i];
        float4 hB = *(const float4*)&h1_s[r1][i];
        float4 b0 = *(const float4*)(wp + (i + 0) * HID);
        float4 b1 = *(const float4*)(wp + (i + 1) * HID);
        float4 b2 = *(const float4*)(wp + (i + 2) * HID);
        float4 b3 = *(const float4*)(wp + (i + 3) * HID);
        fma4(hA.x, b0, aA); fma4(hA.y, b1, aA); fma4(hA.z, b2, aA); fma4(hA.w, b3, aA);
        fma4(hB.x, b0, aB); fma4(hB.y, b1, aB); fma4(hB.z, b2, aB); fma4(hB.w, b3, aB);
      }
      float4 oA, oB;
      oA.x = siluf(aA[0] + b2r.x); oA.y = siluf(aA[1] + b2r.y);
      oA.z = siluf(aA[2] + b2r.z); oA.w = siluf(aA[3] + b2r.w);
      oB.x = siluf(aB[0] + b2r.x); oB.y = siluf(aB[1] + b2r.y);
      oB.z = siluf(aB[2] + b2r.z); oB.w = siluf(aB[3] + b2r.w);
      *(float4*)&h2_s[r0][cg] = oA;
      *(float4*)&h2_s[r1][cg] = oB;
    }
    __syncthreads();   // h2 ready

    // ---- logits + categorical for rows {2w, 2w+1} (per-wave) ----
    {
      float4 hL0 = *(const float4*)&h2_s[2 * w][lane * 4];
      float4 hL1 = *(const float4*)&h2_s[2 * w + 1][lane * 4];
      float pA0 = hL0.x * chw0[0] + hL0.y * chw0[1] + hL0.z * chw0[2] + hL0.w * chw0[3];
      float pA1 = hL0.x * chw1[0] + hL0.y * chw1[1] + hL0.z * chw1[2] + hL0.w * chw1[3];
      float pB0 = hL1.x * chw0[0] + hL1.y * chw0[1] + hL1.z * chw0[2] + hL1.w * chw0[3];
      float pB1 = hL1.x * chw1[0] + hL1.y * chw1[1] + hL1.z * chw1[2] + hL1.w * chw1[3];
      #pragma unroll
      for (int off = 32; off > 0; off >>= 1) {
        pA0 += __shfl_xor(pA0, off);
        pA1 += __shfl_xor(pA1, off);
        pB0 += __shfl_xor(pB0, off);
        pB1 += __shfl_xor(pB1, off);
      }
      u32 grow = (u32)(row0g + 2 * w + ((lane >> 1) & 1));
      float g = gumf(pbits(k2a, k2b, grow * 2u + (u32)(lane & 1)));
      float g0 = __shfl(g, 0), g1 = __shfl(g, 1);
      float g2 = __shfl(g, 2), g3 = __shfl(g, 3);
      if (lane == 0) {
        tcur_s[2 * w]     = (pA1 + cb1 + g1 > pA0 + cb0 + g0) ? 1 : 0;
        tcur_s[2 * w + 1] = (pB1 + cb1 + g3 > pB0 + cb0 + g2) ? 1 : 0;
      }
    }

    // ---- G3 main: score cols 0..255; xy += step*score + sqrt(step)*noise ----
    {
      float sA[4] = {0.f, 0.f, 0.f, 0.f};
      float sB[4] = {0.f, 0.f, 0.f, 0.f};
      const float* wp = sh_w + cg;
      #pragma unroll 4
      for (int i = 0; i < HID; i += 4) {
        float4 hA = *(const float4*)&h2_s[r0][i];
        float4 hB = *(const float4*)&h2_s[r1][i];
        float4 b0 = *(const float4*)(wp + (i + 0) * DXY);
        float4 b1 = *(const float4*)(wp + (i + 1) * DXY);
        float4 b2 = *(const float4*)(wp + (i + 2) * DXY);
        float4 b3 = *(const float4*)(wp + (i + 3) * DXY);
        fma4(hA.x, b0, sA); fma4(hA.y, b1, sA); fma4(hA.z, b2, sA); fma4(hA.w, b3, sA);
        fma4(hB.x, b0, sB); fma4(hB.y, b1, sB); fma4(hB.z, b2, sB); fma4(hB.w, b3, sB);
      }
      const u32 jA = (u32)(row0g + r0) * 288u + (u32)cg;
      const u32 jB = (u32)(row0g + r1) * 288u + (u32)cg;
      float4 xA = *(const float4*)&xy_s[r0][cg];
      float4 xB = *(const float4*)&xy_s[r1][cg];
      xA.x = fmaf(sstep, nrmf(pbits(k1a, k1b, jA + 0u)), fmaf(stepf, sA[0] + sbm.x, xA.x));
      xA.y = fmaf(sstep, nrmf(pbits(k1a, k1b, jA + 1u)), fmaf(stepf, sA[1] + sbm.y, xA.y));
      xA.z = fmaf(sstep, nrmf(pbits(k1a, k1b, jA + 2u)), fmaf(stepf, sA[2] + sbm.z, xA.z));
      xA.w = fmaf(sstep, nrmf(pbits(k1a, k1b, jA + 3u)), fmaf(stepf, sA[3] + sbm.w, xA.w));
      xB.x = fmaf(sstep, nrmf(pbits(k1a, k1b, jB + 0u)), fmaf(stepf, sB[0] + sbm.x, xB.x));
      xB.y = fmaf(sstep, nrmf(pbits(k1a, k1b, jB + 1u)), fmaf(stepf, sB[1] + sbm.y, xB.y));
      xB.z = fmaf(sstep, nrmf(pbits(k1a, k1b, jB + 2u)), fmaf(stepf, sB[2] + sbm.z, xB.z));
      xB.w = fmaf(sstep, nrmf(pbits(k1a, k1b, jB + 3u)), fmaf(stepf, sB[3] + sbm.w, xB.w));
      *(float4*)&xy_s[r0][cg] = xA;
      *(float4*)&xy_s[r1][cg] = xB;
    }

    // ---- G3 extra: cols 256..287 (wave w: 4 cols, all 16 rows) ----
    {
      float sE = 0.f;
      const float* wp = sh_w + cE;
      #pragma unroll 4
      for (int i = 0; i < HID; i += 4) {
        float4 hE = *(const float4*)&h2_s[rE][i];
        const float* bp = wp + i * DXY;
        sE = fmaf(hE.x, bp[0],
             fmaf(hE.y, bp[DXY],
             fmaf(hE.z, bp[2 * DXY],
             fmaf(hE.w, bp[3 * DXY], sE))));
      }
      u32 jE = (u32)(row0g + rE) * 288u + (u32)cE;
      float nE = nrmf(pbits(k1a, k1b, jE));
      xy_s[rE][cE] = fmaf(sstep, nE, fmaf(stepf, sE + sbE, xy_s[rE][cE]));
    }

    // ---- stage Ct for next step ----
    if (t_idx > 1) ((float*)ct_s)[tid] = ws[(t_idx - 1) * 512 + tid];
    __syncthreads();   // xy/tcur/ct ready for next G1
  }

  // ---- final store: x (4096x256), y (4096x32), t (4096) ----
  for (int idx = tid; idx < 16 * 64; idx += NTHR) {
    int r = idx >> 6;
    int c4 = (idx & 63) * 4;
    *(float4*)(out + (row0g + r) * 256 + c4) = *(const float4*)&xy_s[r][c4];
  }
  for (int idx = tid; idx < 16 * 8; idx += NTHR) {
    int r = idx >> 3;
    int c4 = (idx & 7) * 4;
    *(float4*)(out + OUT_Y_OFF + (row0g + r) * 32 + c4) = *(const float4*)&xy_s[r][256 + c4];
  }
  if (tid < 16) out[OUT_T_OFF + row0g + tid] = (float)tcur_s[tid];
}

extern "C" void kernel_launch(void* const* d_in, const int* in_sizes, int n_in,
                              void* d_out, int out_size, void* d_ws, size_t ws_size,
                              hipStream_t stream) {
  (void)in_sizes; (void)n_in; (void)ws_size; (void)out_size;
  const float* xy0     = (const float*)d_in[0];
  const int*   t0      = (const int*)d_in[1];
  const float* t_embed = (const float*)d_in[2];
  const float* tm_w1   = (const float*)d_in[3];
  const float* tm_b1   = (const float*)d_in[4];
  const float* tm_w2   = (const float*)d_in[5];
  const float* tm_b2   = (const float*)d_in[6];
  const float* tr_w1   = (const float*)d_in[7];
  const float* tr_b1   = (const float*)d_in[8];
  const float* tr_w2   = (const float*)d_in[9];
  const float* tr_b2   = (const float*)d_in[10];
  const float* sh_w    = (const float*)d_in[11];
  const float* sh_b    = (const float*)d_in[12];
  const float* ch_w    = (const float*)d_in[13];
  const float* ch_b    = (const float*)d_in[14];
  float* ws  = (float*)d_ws;
  float* out = (float*)d_out;

  precompute_ct<<<49, 256, 0, stream>>>(t_embed, tm_w1, tm_b1, tm_w2, tm_b2,
                                        tr_w1, tr_b1, ws);
  sampler_k<<<256, NTHR, 0, stream>>>(xy0, t0, tr_w1, tr_w2, tr_b2,
                                      sh_w, sh_b, ch_w, ch_b, ws, out);
}